// Round 13
// baseline (247.986 us; speedup 1.0000x reference)
//
#include <hip/hip_runtime.h>
#include <hip/hip_bf16.h>

#define D 128
#define SPANMAX 192
#define NBUCK 65536        // seed>>4 buckets (16-row spans)
#define W1F_ELEMS 81920    // 20*8*64*8
#define W2F_ELEMS 16384    // 4*8*64*8

typedef __attribute__((ext_vector_type(8))) short bf16x8;
typedef __attribute__((ext_vector_type(4))) float f32x4;

static __device__ __forceinline__ unsigned short f32_to_bf16(float f) {
    unsigned u = __float_as_uint(f);
    unsigned r = u + 0x7FFFu + ((u >> 16) & 1u);   // RNE
    return (unsigned short)(r >> 16);
}

static __device__ __forceinline__ unsigned pack_bf16x2(float a, float b) {
    __hip_bfloat162 h = __float22bfloat162_rn(make_float2(a, b));  // v_cvt_pk_bf16_f32
    return *reinterpret_cast<unsigned*>(&h);
}

// Pack W1 [128][640] and W2 [128][128] (fp32, torch Linear [out,in]) into MFMA
// B-fragment order: (ks, j16, lane, e) = W[j16*16 + (lane&15)][ks*32 + (lane>>4)*8 + e]
__global__ void prep_frags(const float* __restrict__ W1, const float* __restrict__ W2,
                           unsigned short* __restrict__ W1f, unsigned short* __restrict__ W2f) {
    int f = blockIdx.x * 256 + threadIdx.x;
    if (f < W1F_ELEMS) {
        int e = f & 7, l = (f >> 3) & 63, j16 = (f >> 9) & 7, ks = f >> 12;
        int o = j16 * 16 + (l & 15);
        int k = ks * 32 + ((l >> 4) << 3) + e;
        W1f[f] = f32_to_bf16(W1[o * 640 + k]);
    } else if (f < W1F_ELEMS + W2F_ELEMS) {
        int f2 = f - W1F_ELEMS;
        int e = f2 & 7, l = (f2 >> 3) & 63, j16 = (f2 >> 9) & 7, ks = f2 >> 12;
        int o = j16 * 16 + (l & 15);
        int k = ks * 32 + ((l >> 4) << 3) + e;
        W2f[f2] = f32_to_bf16(W2[o * D + k]);
    }
}

// ---- counting sort by bucket (seed>>4), carrying original index ----
__global__ void zero_counts(int* __restrict__ counts) {
    counts[blockIdx.x * 256 + threadIdx.x] = 0;
}

__global__ void hist_kernel(const int* __restrict__ seeds, int* __restrict__ counts, int B) {
    int i = blockIdx.x * 256 + threadIdx.x;
    if (i < B) atomicAdd(&counts[seeds[i] >> 4], 1);
}

// one block, 1024 threads, 64 buckets each: exclusive prefix over 65536
__global__ __launch_bounds__(1024) void scan_kernel(const int* __restrict__ counts,
                                                    int* __restrict__ offsets) {
    __shared__ int tsum[1024];
    const int tid = threadIdx.x;
    const int base = tid * 64;
    int s = 0;
    for (int i = 0; i < 64; ++i) s += counts[base + i];
    tsum[tid] = s;
    __syncthreads();
    for (int off = 1; off < 1024; off <<= 1) {
        int v = 0;
        if (tid >= off) v = tsum[tid - off];
        __syncthreads();
        if (tid >= off) tsum[tid] += v;
        __syncthreads();
    }
    int run = tsum[tid] - s;
    for (int i = 0; i < 64; ++i) { offsets[base + i] = run; run += counts[base + i]; }
}

__global__ void scatter_kernel(const int* __restrict__ seeds, int* __restrict__ offsets,
                               int2* __restrict__ sorted, int B) {
    int i = blockIdx.x * 256 + threadIdx.x;
    if (i < B) {
        int s = seeds[i];
        int pos = atomicAdd(&offsets[s >> 4], 1);
        sorted[pos] = make_int2(s, i);
    }
}

// R13: SEQUENTIAL-STREAM gather. Block = 32 bucket-sorted seeds; their
// windows' union is ~125 contiguous rows. STREAM path: read rows [lo,hi]
// once, fully coalesced (fill-kernel regime, 87% of peak measured), convert
// to bf16 into a 192-row LDS tile; A-fragments are per-lane LDS reads at
// dynamic row offsets (precomputed rA*, XOR-swizzled). FALLBACK (span>192,
// ~1% of blocks): per-seed 5-row windows into the same tile at rows
// sidx*5+j (160<=192), same COMPUTE. Both paths: identical accumulation
// order => bit-identical, deterministic output despite scatter-order
// nondeterminism. LDS 49.4 KB -> 3 blocks/CU.
__global__ __launch_bounds__(256, 3) void rowmlp_kernel(
    const float* __restrict__ x_rows, const int2* __restrict__ sorted,
    const unsigned short* __restrict__ W1f, const float* __restrict__ b1,
    const unsigned short* __restrict__ W2f, const float* __restrict__ b2,
    float* __restrict__ out, int Nrows)
{
    __shared__ __align__(16) unsigned short tile[SPANMAX * 128];  // 48 KB bf16
    __shared__ int sseed[32], sorg[32], sctl[2];

    const int tid = threadIdx.x;
    // chunked XCD swizzle: 8192 blocks % 8 == 0 -> each XCD gets a contiguous
    // 1024-block range of sorted row-space (L2-local boundary overlap)
    const int blk = (blockIdx.x & 7) * 1024 + (blockIdx.x >> 3);

    // prologue: wave 0 loads the 32 (seed,orig) pairs + min/max reduce
    if (tid < 64) {
        int2 p = sorted[blk * 32 + (tid & 31)];
        if (tid < 32) { sseed[tid] = p.x; sorg[tid] = p.y; }
        int mn = p.x, mx = p.x;
        #pragma unroll
        for (int k = 32; k >= 1; k >>= 1) {
            mn = min(mn, __shfl_xor(mn, k));
            mx = max(mx, __shfl_xor(mx, k));
        }
        if (tid == 0) {
            int lo = mn - 2; lo = lo < 0 ? 0 : lo;
            int hi = mx + 2; hi = hi > Nrows - 1 ? Nrows - 1 : hi;
            sctl[0] = lo; sctl[1] = hi - lo + 1;
        }
    }
    __syncthreads();

    const int lo = sctl[0], span = sctl[1];
    const bool stream = (span <= SPANMAX);

    const int w   = tid >> 6;
    const int l   = tid & 63;
    const int l15 = l & 15;
    const int lhi = l >> 4;

    // per-thread A-row indices in the tile, both m-halves x 5 neighbors
    int rA0[5], rA1[5];
    {
        const int s0 = sseed[l15], s1 = sseed[16 + l15];
        #pragma unroll
        for (int j = 0; j < 5; ++j) {
            if (stream) {
                int i0 = s0 + j - 2; i0 = i0 < 0 ? 0 : (i0 > Nrows - 1 ? Nrows - 1 : i0);
                int i1 = s1 + j - 2; i1 = i1 < 0 ? 0 : (i1 > Nrows - 1 ? Nrows - 1 : i1);
                rA0[j] = i0 - lo; rA1[j] = i1 - lo;
            } else {
                rA0[j] = l15 * 5 + j; rA1[j] = (16 + l15) * 5 + j;
            }
        }
    }

    // ---- staging: fp32 -> bf16 into tile (16B chunk q = row*16 + c)
    if (stream) {
        const int total = span * 16;
        #pragma unroll
        for (int it = 0; it < 12; ++it) {
            int q = tid + it * 256;
            if (q < total) {
                int row = q >> 4, c = q & 15;
                const float4* src = (const float4*)(x_rows + (size_t)(lo + row) * D + c * 8);
                float4 v0 = src[0], v1 = src[1];
                union { unsigned u[4]; bf16x8 v; } pk;
                pk.u[0] = pack_bf16x2(v0.x, v0.y); pk.u[1] = pack_bf16x2(v0.z, v0.w);
                pk.u[2] = pack_bf16x2(v1.x, v1.y); pk.u[3] = pack_bf16x2(v1.z, v1.w);
                *(bf16x8*)(&tile[row * 128 + ((c ^ (row & 7)) * 8)]) = pk.v;
            }
        }
    } else {
        #pragma unroll
        for (int it = 0; it < 10; ++it) {
            int q = tid + it * 256;            // < 2560
            int rw = q >> 4, c = q & 15;
            int sidx = (rw * 205) >> 10;       // rw/5, exact for rw<160
            int j = rw - sidx * 5;
            int sr = sseed[sidx] + j - 2;
            sr = sr < 0 ? 0 : (sr > Nrows - 1 ? Nrows - 1 : sr);
            const float4* src = (const float4*)(x_rows + (size_t)sr * D + c * 8);
            float4 v0 = src[0], v1 = src[1];
            union { unsigned u[4]; bf16x8 v; } pk;
            pk.u[0] = pack_bf16x2(v0.x, v0.y); pk.u[1] = pack_bf16x2(v0.z, v0.w);
            pk.u[2] = pack_bf16x2(v1.x, v1.y); pk.u[3] = pack_bf16x2(v1.z, v1.w);
            *(bf16x8*)(&tile[rw * 128 + ((c ^ (rw & 7)) * 8)]) = pk.v;
        }
    }
    __syncthreads();

    const bf16x8* W1v = (const bf16x8*)W1f;
    const bf16x8* W2v = (const bf16x8*)W2f;

    // ---- GEMM1: h = x_cat @ W1^T  (M=32, N=32/wave, K=640), A from tile
    f32x4 acc[2][2] = {};
    #pragma unroll
    for (int j = 0; j < 5; ++j) {
        const int r0 = rA0[j], r1 = rA1[j];
        #pragma unroll
        for (int ks = 0; ks < 4; ++ks) {
            const int ch = ks * 4 + lhi;
            bf16x8 a0 = *(const bf16x8*)(&tile[r0 * 128 + ((ch ^ (r0 & 7)) * 8)]);
            bf16x8 a1 = *(const bf16x8*)(&tile[r1 * 128 + ((ch ^ (r1 & 7)) * 8)]);
            #pragma unroll
            for (int n = 0; n < 2; ++n) {
                bf16x8 b = W1v[((j * 4 + ks) * 8 + (w * 2 + n)) * 64 + l];
                acc[0][n] = __builtin_amdgcn_mfma_f32_16x16x32_bf16(a0, b, acc[0][n], 0, 0, 0);
                acc[1][n] = __builtin_amdgcn_mfma_f32_16x16x32_bf16(a1, b, acc[1][n], 0, 0, 0);
            }
        }
    }
    __syncthreads();   // tile reads done before Hb alias writes

    // ---- bias + ReLU -> bf16 Hb (aliases tile rows 0..31)
    unsigned short (*Hb)[128] = (unsigned short (*)[128])tile;
    #pragma unroll
    for (int n = 0; n < 2; ++n) {
        const int col = w * 32 + n * 16 + l15;
        const float bias = b1[col];
        #pragma unroll
        for (int m = 0; m < 2; ++m) {
            #pragma unroll
            for (int r = 0; r < 4; ++r) {
                float v = acc[m][n][r] + bias;
                v = v > 0.f ? v : 0.f;
                const int row = m * 16 + lhi * 4 + r;  // C/D: col=lane&15, row=(lane>>4)*4+reg
                Hb[row][col ^ ((row & 7) << 3)] = f32_to_bf16(v);
            }
        }
    }
    __syncthreads();

    // ---- GEMM2: out = h @ W2^T  (M=32, N=32/wave, K=128) — reuse acc
    #pragma unroll
    for (int m = 0; m < 2; ++m)
        #pragma unroll
        for (int n = 0; n < 2; ++n)
            acc[m][n] = (f32x4){0.f, 0.f, 0.f, 0.f};
    #pragma unroll
    for (int ks = 0; ks < 4; ++ks) {
        bf16x8 a2[2], bb[2];
        #pragma unroll
        for (int m = 0; m < 2; ++m) {
            const int row = m * 16 + l15;
            a2[m] = *(const bf16x8*)(&Hb[row][(ks * 32 + lhi * 8) ^ ((row & 7) << 3)]);
        }
        #pragma unroll
        for (int n = 0; n < 2; ++n)
            bb[n] = W2v[(ks * 8 + (w * 2 + n)) * 64 + l];
        #pragma unroll
        for (int m = 0; m < 2; ++m)
            #pragma unroll
            for (int n = 0; n < 2; ++n)
                acc[m][n] = __builtin_amdgcn_mfma_f32_16x16x32_bf16(a2[m], bb[n], acc[m][n], 0, 0, 0);
    }

    // ---- bias + fp32 store to ORIGINAL rows
    #pragma unroll
    for (int n = 0; n < 2; ++n) {
        const int col = w * 32 + n * 16 + l15;
        const float bias = b2[col];
        #pragma unroll
        for (int m = 0; m < 2; ++m) {
            #pragma unroll
            for (int r = 0; r < 4; ++r) {
                const int row = m * 16 + lhi * 4 + r;
                out[(size_t)sorg[row] * D + col] = acc[m][n][r] + bias;
            }
        }
    }
}

extern "C" void kernel_launch(void* const* d_in, const int* in_sizes, int n_in,
                              void* d_out, int out_size, void* d_ws, size_t ws_size,
                              hipStream_t stream) {
    const float* x_rows = (const float*)d_in[0];
    const int*   seeds  = (const int*)d_in[1];
    const float* W1     = (const float*)d_in[2];
    const float* b1     = (const float*)d_in[3];
    const float* W2     = (const float*)d_in[4];
    const float* b2     = (const float*)d_in[5];
    float* out = (float*)d_out;

    int Nrows = in_sizes[0] / D;
    int B = in_sizes[1];

    // d_ws layout
    unsigned short* W1f = (unsigned short*)d_ws;                 // 160 KB
    unsigned short* W2f = W1f + W1F_ELEMS;                       // 32 KB
    int* counts  = (int*)(W2f + W2F_ELEMS);                      // 256 KB
    int* offsets = counts + NBUCK;                               // 256 KB
    int2* sorted = (int2*)(offsets + NBUCK);                     // 8*B = 2 MB

    prep_frags<<<(W1F_ELEMS + W2F_ELEMS + 255) / 256, 256, 0, stream>>>(W1, W2, W1f, W2f);
    zero_counts<<<NBUCK / 256, 256, 0, stream>>>(counts);
    hist_kernel<<<(B + 255) / 256, 256, 0, stream>>>(seeds, counts, B);
    scan_kernel<<<1, 1024, 0, stream>>>(counts, offsets);
    scatter_kernel<<<(B + 255) / 256, 256, 0, stream>>>(seeds, offsets, sorted, B);
    rowmlp_kernel<<<B / 32, 256, 0, stream>>>(x_rows, sorted, W1f, b1, W2f, b2, out, Nrows);
}

// Round 14
// 183.326 us; speedup vs baseline: 1.3527x; 1.3527x over previous
//
#include <hip/hip_runtime.h>
#include <hip/hip_bf16.h>

#define D 128
#define CAT 640
#define BM 32
#define W1F_ELEMS 81920    // 20*8*64*8
#define W2F_ELEMS 16384    // 4*8*64*8

typedef __attribute__((ext_vector_type(8))) short bf16x8;
typedef __attribute__((ext_vector_type(4))) float f32x4;

static __device__ __forceinline__ unsigned short f32_to_bf16(float f) {
    unsigned u = __float_as_uint(f);
    unsigned r = u + 0x7FFFu + ((u >> 16) & 1u);   // RNE
    return (unsigned short)(r >> 16);
}

static __device__ __forceinline__ unsigned pack_bf16x2(float a, float b) {
    __hip_bfloat162 h = __float22bfloat162_rn(make_float2(a, b));  // v_cvt_pk_bf16_f32
    return *reinterpret_cast<unsigned*>(&h);
}

// async global->LDS, 16B per lane, wave-uniform LDS base + lane*16
static __device__ __forceinline__ void gload_lds16(const float* g, void* lds) {
    __builtin_amdgcn_global_load_lds(
        (const __attribute__((address_space(1))) void*)g,
        (__attribute__((address_space(3))) void*)lds, 16, 0, 0);
}

// Pack W1 [128][640] and W2 [128][128] (fp32, torch Linear [out,in]) into MFMA
// B-fragment order: (ks, j16, lane, e) = W[j16*16 + (lane&15)][ks*32 + (lane>>4)*8 + e]
__global__ void prep_frags(const float* __restrict__ W1, const float* __restrict__ W2,
                           unsigned short* __restrict__ W1f, unsigned short* __restrict__ W2f) {
    int f = blockIdx.x * 256 + threadIdx.x;
    if (f < W1F_ELEMS) {
        int e = f & 7, l = (f >> 3) & 63, j16 = (f >> 9) & 7, ks = f >> 12;
        int o = j16 * 16 + (l & 15);
        int k = ks * 32 + ((l >> 4) << 3) + e;
        W1f[f] = f32_to_bf16(W1[o * CAT + k]);
    } else if (f < W1F_ELEMS + W2F_ELEMS) {
        int f2 = f - W1F_ELEMS;
        int e = f2 & 7, l = (f2 >> 3) & 63, j16 = (f2 >> 9) & 7, ks = f2 >> 12;
        int o = j16 * 16 + (l & 15);
        int k = ks * 32 + ((l >> 4) << 3) + e;
        W2f[f2] = f32_to_bf16(W2[o * D + k]);
    }
}

// FINAL (R11, best measured 183.0us): bulk coalesced async gather via
// global_load_lds (2 contiguous 512B rows per instr), double-buffered LDS,
// W1 fragments double-buffered in registers so COMPUTE has zero vmem ops,
// vmcnt(0)+barrier per chunk, Hb aliased into smem[1], 4 blocks/CU.
// A/B-tested effects: coalesced staging (+23us if scattered), W1-in-regs
// (-7..-10us), depth-2/sort/stream/occupancy variants all null or worse.
__global__ __launch_bounds__(256, 4) void rowmlp_kernel(
    const float* __restrict__ x_rows, const int* __restrict__ seeds,
    const unsigned short* __restrict__ W1f, const float* __restrict__ b1,
    const unsigned short* __restrict__ W2f, const float* __restrict__ b2,
    float* __restrict__ out, int Nrows)
{
    __shared__ __align__(16) unsigned char smem[2][16384];
    __shared__ int sseed[BM];

    const int tid = threadIdx.x;
    const int blk = blockIdx.x;

    if (tid < BM) sseed[tid] = seeds[blk * BM + tid];
    __syncthreads();

    const int w   = tid >> 6;    // wave: stages rows 8w..8w+7; owns cols 32w..32w+31
    const int l   = tid & 63;
    const int l15 = l & 15;
    const int lhi = l >> 4;

    // staging geometry: instr i covers rows 8w+2i, 8w+2i+1;
    // lane covers 16B chunk c=l&31 of its row; source chunk pre-swizzled c^(r&7).
    int sbase[4], scoff[4];
    #pragma unroll
    for (int i = 0; i < 4; ++i) {
        int r = 8 * w + 2 * i + (l >> 5);
        sbase[i] = sseed[r];
        scoff[i] = ((l & 31) ^ (r & 7)) << 2;   // float offset within row
    }

    const bf16x8* W1v = (const bf16x8*)W1f;
    const bf16x8* W2v = (const bf16x8*)W2f;

#define WAIT0 asm volatile("s_waitcnt vmcnt(0)" ::: "memory")
#define BAR   __builtin_amdgcn_s_barrier()

#define ISSUE(J)                                                               \
    {                                                                          \
        _Pragma("unroll")                                                      \
        for (int i = 0; i < 4; ++i) {                                          \
            int idx = sbase[i] + (J) - 2;                                      \
            idx = idx < 0 ? 0 : (idx >= Nrows ? Nrows - 1 : idx);              \
            gload_lds16(x_rows + (size_t)idx * D + scoff[i],                   \
                        (void*)(smem[(J) & 1] + w * 4096 + i * 1024));         \
        }                                                                      \
    }

#define LOADW1(J, RB)                                                          \
    {                                                                          \
        _Pragma("unroll")                                                      \
        for (int ks = 0; ks < 4; ++ks)                                         \
            _Pragma("unroll")                                                  \
            for (int n = 0; n < 2; ++n)                                        \
                w1r[RB][ks][n] = W1v[(((J) * 4 + ks) * 8 + (w * 2 + n)) * 64 + l]; \
    }

#define COMPUTE(BUF, RB)                                                       \
    {                                                                          \
        const float* buf = (const float*)smem[BUF];                            \
        _Pragma("unroll")                                                      \
        for (int ks = 0; ks < 4; ++ks) {                                       \
            bf16x8 a[2];                                                       \
            _Pragma("unroll")                                                  \
            for (int m = 0; m < 2; ++m) {                                      \
                const int r = m * 16 + l15;                                    \
                const int s = r & 7;                                           \
                const int cc = ks * 8 + lhi * 2;                               \
                float4 q0 = *(const float4*)(buf + r * 128 + (((cc) ^ s) << 2));     \
                float4 q1 = *(const float4*)(buf + r * 128 + (((cc + 1) ^ s) << 2)); \
                union { unsigned u[4]; bf16x8 v; } pk;                         \
                pk.u[0] = pack_bf16x2(q0.x, q0.y);                             \
                pk.u[1] = pack_bf16x2(q0.z, q0.w);                             \
                pk.u[2] = pack_bf16x2(q1.x, q1.y);                             \
                pk.u[3] = pack_bf16x2(q1.z, q1.w);                             \
                a[m] = pk.v;                                                   \
            }                                                                  \
            _Pragma("unroll")                                                  \
            for (int n = 0; n < 2; ++n)                                        \
                _Pragma("unroll")                                              \
                for (int m = 0; m < 2; ++m)                                    \
                    acc[m][n] = __builtin_amdgcn_mfma_f32_16x16x32_bf16(       \
                        a[m], w1r[RB][ks][n], acc[m][n], 0, 0, 0);             \
        }                                                                      \
    }

    bf16x8 w1r[2][4][2];
    f32x4 acc[2][2] = {};

    // prologue: gather chunk 0, W1 regs for chunk 0
    ISSUE(0)
    LOADW1(0, 0)

    // j=0
    WAIT0; BAR;
    ISSUE(1) LOADW1(1, 1)
    COMPUTE(0, 0)
    // j=1
    WAIT0; BAR;
    ISSUE(2) LOADW1(2, 0)
    COMPUTE(1, 1)
    // j=2
    WAIT0; BAR;
    ISSUE(3) LOADW1(3, 1)
    COMPUTE(0, 0)
    // j=3
    WAIT0; BAR;
    ISSUE(4) LOADW1(4, 0)
    COMPUTE(1, 1)
    // j=4
    WAIT0; BAR;
    COMPUTE(0, 0)

    // ---- epilogue: bias + ReLU -> bf16 Hb aliased into smem[1]
    // (chunk-3 buffer, all waves done with it; chunk-4 readers use smem[0]).
    unsigned short (*Hb)[D] = (unsigned short (*)[D])smem[1];
    #pragma unroll
    for (int n = 0; n < 2; ++n) {
        const int col = w * 32 + n * 16 + l15;
        const float bias = b1[col];
        #pragma unroll
        for (int m = 0; m < 2; ++m) {
            #pragma unroll
            for (int r = 0; r < 4; ++r) {
                float v = acc[m][n][r] + bias;
                v = v > 0.f ? v : 0.f;
                const int row = m * 16 + lhi * 4 + r;  // C/D: col=lane&15, row=(lane>>4)*4+reg
                Hb[row][col ^ ((row & 7) << 3)] = f32_to_bf16(v);
            }
        }
    }
    __syncthreads();

    // GEMM2: out = h @ W2^T  (M=32, N=32/wave, K=128) — reuse acc as accumulator
    #pragma unroll
    for (int m = 0; m < 2; ++m)
        #pragma unroll
        for (int n = 0; n < 2; ++n)
            acc[m][n] = (f32x4){0.f, 0.f, 0.f, 0.f};
    #pragma unroll
    for (int ks = 0; ks < 4; ++ks) {
        bf16x8 a2[2], bb[2];
        #pragma unroll
        for (int m = 0; m < 2; ++m) {
            const int row = m * 16 + l15;
            a2[m] = *(const bf16x8*)(&Hb[row][(ks * 32 + lhi * 8) ^ ((row & 7) << 3)]);
        }
        #pragma unroll
        for (int n = 0; n < 2; ++n) {
            const int j16 = w * 2 + n;
            bb[n] = W2v[(ks * 8 + j16) * 64 + l];
        }
        #pragma unroll
        for (int m = 0; m < 2; ++m)
            #pragma unroll
            for (int n = 0; n < 2; ++n)
                acc[m][n] = __builtin_amdgcn_mfma_f32_16x16x32_bf16(a2[m], bb[n], acc[m][n], 0, 0, 0);
    }

    // bias + fp32 store
    #pragma unroll
    for (int n = 0; n < 2; ++n) {
        const int col = w * 32 + n * 16 + l15;
        const float bias = b2[col];
        #pragma unroll
        for (int m = 0; m < 2; ++m) {
            #pragma unroll
            for (int r = 0; r < 4; ++r) {
                const int row = m * 16 + lhi * 4 + r;
                out[(size_t)(blk * BM + row) * D + col] = acc[m][n][r] + bias;
            }
        }
    }
#undef ISSUE
#undef LOADW1
#undef COMPUTE
#undef WAIT0
#undef BAR
}

extern "C" void kernel_launch(void* const* d_in, const int* in_sizes, int n_in,
                              void* d_out, int out_size, void* d_ws, size_t ws_size,
                              hipStream_t stream) {
    const float* x_rows = (const float*)d_in[0];
    const int*   seeds  = (const int*)d_in[1];
    const float* W1     = (const float*)d_in[2];
    const float* b1     = (const float*)d_in[3];
    const float* W2     = (const float*)d_in[4];
    const float* b2     = (const float*)d_in[5];
    float* out = (float*)d_out;

    int Nrows = in_sizes[0] / D;
    int B = in_sizes[1];

    unsigned short* W1f = (unsigned short*)d_ws;
    unsigned short* W2f = W1f + W1F_ELEMS;

    prep_frags<<<(W1F_ELEMS + W2F_ELEMS + 255) / 256, 256, 0, stream>>>(W1, W2, W1f, W2f);
    rowmlp_kernel<<<B / BM, 256, 0, stream>>>(x_rows, seeds, W1f, b1, W2f, b2, out, Nrows);
}